// Round 1
// baseline (2603.116 us; speedup 1.0000x reference)
//
#include <hip/hip_runtime.h>
#include <stdint.h>

#define N_NODES 100000
#define N_EDGES 640000
#define R_REL   64
#define D_DIM   128
#define L_LAYERS 2

typedef __attribute__((ext_vector_type(8))) short   short8;   // 8 bf16 (4 VGPRs) MFMA frag
typedef __attribute__((ext_vector_type(4))) unsigned short ushort4v;
typedef __attribute__((ext_vector_type(4))) float   f32x4;

__device__ __forceinline__ unsigned short f32_to_bf16(float f) {
  union { float f; uint32_t u; } v; v.f = f;
  uint32_t u = v.u;
  u += 0x7fffu + ((u >> 16) & 1u);   // RNE (finite inputs only)
  return (unsigned short)(u >> 16);
}

__device__ __forceinline__ short8 pack8(const float* __restrict__ p) {
  float4 u0 = *(const float4*)p;
  float4 u1 = *(const float4*)(p + 4);
  short8 r;
  r[0] = (short)f32_to_bf16(u0.x); r[1] = (short)f32_to_bf16(u0.y);
  r[2] = (short)f32_to_bf16(u0.z); r[3] = (short)f32_to_bf16(u0.w);
  r[4] = (short)f32_to_bf16(u1.x); r[5] = (short)f32_to_bf16(u1.y);
  r[6] = (short)f32_to_bf16(u1.z); r[7] = (short)f32_to_bf16(u1.w);
  return r;
}

// ---------------------------------------------------------------------------
// Kernel A: gamma/beta for both layers. grid = L*R blocks x 256 threads.
// h0=relu(rmw0@rel+b0); h1=relu(rmw1@h0+b1); h2=relu(rmw2@h1+b2); gb=rmw3@h2+b3
// gamma = gb[:, :D], beta = gb[:, D:]. All f32 exact.
// ---------------------------------------------------------------------------
__global__ __launch_bounds__(256)
void gamma_beta_kernel(const float* __restrict__ rel_emb,
                       const float* __restrict__ rmw0, const float* __restrict__ rmb0,
                       const float* __restrict__ rmw1, const float* __restrict__ rmb1,
                       const float* __restrict__ rmw2, const float* __restrict__ rmb2,
                       const float* __restrict__ rmw3, const float* __restrict__ rmb3,
                       float* __restrict__ gamma, float* __restrict__ beta) {
  __shared__ float bufA[2 * D_DIM];
  __shared__ float bufB[2 * D_DIM];
  const int l = blockIdx.x >> 6;
  const int r = blockIdx.x & 63;
  const int j = threadIdx.x;   // 0..255

  if (j < D_DIM) bufA[j] = rel_emb[(l * R_REL + r) * D_DIM + j];
  __syncthreads();

  // h0: dot(rmw0[l][j][:], rel) over 128
  {
    const float* w = rmw0 + ((size_t)l * 2 * D_DIM + j) * D_DIM;
    float s = rmb0[l * 2 * D_DIM + j];
    for (int k = 0; k < D_DIM; k += 4) {
      float4 wv = *(const float4*)(w + k);
      s += wv.x * bufA[k] + wv.y * bufA[k + 1] + wv.z * bufA[k + 2] + wv.w * bufA[k + 3];
    }
    bufB[j] = fmaxf(s, 0.0f);
  }
  __syncthreads();
  // h1: dot over 256
  {
    const float* w = rmw1 + ((size_t)l * 2 * D_DIM + j) * 2 * D_DIM;
    float s = rmb1[l * 2 * D_DIM + j];
    for (int k = 0; k < 2 * D_DIM; k += 4) {
      float4 wv = *(const float4*)(w + k);
      s += wv.x * bufB[k] + wv.y * bufB[k + 1] + wv.z * bufB[k + 2] + wv.w * bufB[k + 3];
    }
    __syncthreads();
    bufA[j] = fmaxf(s, 0.0f);
  }
  __syncthreads();
  // h2
  {
    const float* w = rmw2 + ((size_t)l * 2 * D_DIM + j) * 2 * D_DIM;
    float s = rmb2[l * 2 * D_DIM + j];
    for (int k = 0; k < 2 * D_DIM; k += 4) {
      float4 wv = *(const float4*)(w + k);
      s += wv.x * bufA[k] + wv.y * bufA[k + 1] + wv.z * bufA[k + 2] + wv.w * bufA[k + 3];
    }
    __syncthreads();
    bufB[j] = fmaxf(s, 0.0f);
  }
  __syncthreads();
  // gb
  {
    const float* w = rmw3 + ((size_t)l * 2 * D_DIM + j) * 2 * D_DIM;
    float s = rmb3[l * 2 * D_DIM + j];
    for (int k = 0; k < 2 * D_DIM; k += 4) {
      float4 wv = *(const float4*)(w + k);
      s += wv.x * bufB[k] + wv.y * bufB[k + 1] + wv.z * bufB[k + 2] + wv.w * bufB[k + 3];
    }
    if (j < D_DIM) gamma[(l * R_REL + r) * D_DIM + j] = s;
    else           beta[(l * R_REL + r) * D_DIM + (j - D_DIM)] = s;
  }
}

// ---------------------------------------------------------------------------
// Kernel B: xw = x @ Ww^T + Wb  (N x 128), plus out = (1+eps)*x.
// 32 rows/block, 4 waves, each wave 32 rows x 32 cols (2x2 MFMA tiles).
// A staged bf16 in LDS; B loaded direct from global (L2-hot 64KB weight).
// ---------------------------------------------------------------------------
#define LDA 136   // 128 + 8 pad (bf16 elems): 2-way-max bank aliasing

__global__ __launch_bounds__(256)
void xw_kernel(const float* __restrict__ x,
               const float* __restrict__ Ww,   // 128x128 layer slice
               const float* __restrict__ Wb,   // 128
               const float* __restrict__ eps,  // &eps[l]
               float* __restrict__ xw,
               float* __restrict__ outinit) {
  __shared__ unsigned short a_lds[32 * LDA];
  const int tid = threadIdx.x;
  const int m0 = blockIdx.x * 32;

  // stage x tile: 32 rows x 128 cols f32 -> bf16
  for (int i = tid; i < 1024; i += 256) {
    int row = i >> 5, ch = i & 31;
    float4 v = *(const float4*)&x[(m0 + row) * D_DIM + ch * 4];
    ushort4v s;
    s[0] = f32_to_bf16(v.x); s[1] = f32_to_bf16(v.y);
    s[2] = f32_to_bf16(v.z); s[3] = f32_to_bf16(v.w);
    *(ushort4v*)&a_lds[row * LDA + ch * 4] = s;
  }
  __syncthreads();

  const int wave = tid >> 6, lane = tid & 63;
  const int lrow = lane & 15, quad = lane >> 4;
  const int n0 = wave * 32;

  f32x4 acc[2][2] = {};
  for (int ks = 0; ks < 128; ks += 32) {
    short8 a0 = *(const short8*)&a_lds[lrow * LDA + ks + quad * 8];
    short8 a1 = *(const short8*)&a_lds[(16 + lrow) * LDA + ks + quad * 8];
    short8 b0 = pack8(Ww + (n0 + lrow) * D_DIM + ks + quad * 8);
    short8 b1 = pack8(Ww + (n0 + 16 + lrow) * D_DIM + ks + quad * 8);
    acc[0][0] = __builtin_amdgcn_mfma_f32_16x16x32_bf16(a0, b0, acc[0][0], 0, 0, 0);
    acc[0][1] = __builtin_amdgcn_mfma_f32_16x16x32_bf16(a0, b1, acc[0][1], 0, 0, 0);
    acc[1][0] = __builtin_amdgcn_mfma_f32_16x16x32_bf16(a1, b0, acc[1][0], 0, 0, 0);
    acc[1][1] = __builtin_amdgcn_mfma_f32_16x16x32_bf16(a1, b1, acc[1][1], 0, 0, 0);
  }

  for (int mt = 0; mt < 2; ++mt)
    for (int nt = 0; nt < 2; ++nt)
      for (int rr = 0; rr < 4; ++rr) {
        int row = mt * 16 + quad * 4 + rr;
        int col = n0 + nt * 16 + lrow;
        xw[(m0 + row) * D_DIM + col] = acc[mt][nt][rr] + Wb[col];
      }

  // out = (1+eps)*x  (exact f32 re-read; x tile is L2-hot)
  const float e1 = 1.0f + eps[0];
  for (int i = tid; i < 1024; i += 256) {
    int row = i >> 5, ch = i & 31;
    float4 v = *(const float4*)&x[(m0 + row) * D_DIM + ch * 4];
    float4 o; o.x = e1 * v.x; o.y = e1 * v.y; o.z = e1 * v.z; o.w = e1 * v.w;
    *(float4*)&outinit[(m0 + row) * D_DIM + ch * 4] = o;
  }
}

// ---------------------------------------------------------------------------
// Kernel C: edge scatter. m = gamma[t]*xw[src] + beta[t]; out[dst] += m.
// 32 lanes per edge (4 cols each, float4), 8 edges/block, HW f32 atomics.
// ---------------------------------------------------------------------------
__global__ __launch_bounds__(256)
void edge_kernel(const int* __restrict__ ei, const int* __restrict__ et,
                 const float* __restrict__ xw,
                 const float* __restrict__ gamma, const float* __restrict__ beta,
                 float* __restrict__ out) {
  const int tid = threadIdx.x;
  const int e = blockIdx.x * 8 + (tid >> 5);
  const int c = (tid & 31) * 4;
  const int src = ei[e];
  const int dst = ei[N_EDGES + e];
  const int t = et[e];
  float4 g = *(const float4*)&gamma[t * D_DIM + c];
  float4 b = *(const float4*)&beta[t * D_DIM + c];
  float4 xv = *(const float4*)&xw[src * D_DIM + c];
  float* o = out + dst * D_DIM + c;
  unsafeAtomicAdd(o + 0, g.x * xv.x + b.x);
  unsafeAtomicAdd(o + 1, g.y * xv.y + b.y);
  unsafeAtomicAdd(o + 2, g.z * xv.z + b.z);
  unsafeAtomicAdd(o + 3, g.w * xv.w + b.w);
}

// ---------------------------------------------------------------------------
// Kernel D: fused node MLP. y = relu(in @ w0^T + b0) @ w1^T + b1.
// 32 rows/block; t (32x256) kept in LDS as bf16. Safe for y == in (row-local).
// ---------------------------------------------------------------------------
#define LDT 264   // 256 + 8 pad

__global__ __launch_bounds__(256)
void mlp_kernel(const float* __restrict__ in,
                const float* __restrict__ w0, const float* __restrict__ b0,  // 256x128, 256
                const float* __restrict__ w1, const float* __restrict__ b1,  // 128x256, 128
                float* __restrict__ y) {
  __shared__ unsigned short a_lds[32 * LDA];
  __shared__ unsigned short t_lds[32 * LDT];
  const int tid = threadIdx.x;
  const int m0 = blockIdx.x * 32;

  for (int i = tid; i < 1024; i += 256) {
    int row = i >> 5, ch = i & 31;
    float4 v = *(const float4*)&in[(m0 + row) * D_DIM + ch * 4];
    ushort4v s;
    s[0] = f32_to_bf16(v.x); s[1] = f32_to_bf16(v.y);
    s[2] = f32_to_bf16(v.z); s[3] = f32_to_bf16(v.w);
    *(ushort4v*)&a_lds[row * LDA + ch * 4] = s;
  }
  __syncthreads();

  const int wave = tid >> 6, lane = tid & 63;
  const int lrow = lane & 15, quad = lane >> 4;

  // phase 1: t = relu(in @ w0^T + b0); wave covers cols [wave*64, wave*64+64)
  {
    const int n0 = wave * 64;
    f32x4 acc[2][4] = {};
    for (int ks = 0; ks < 128; ks += 32) {
      short8 a0 = *(const short8*)&a_lds[lrow * LDA + ks + quad * 8];
      short8 a1 = *(const short8*)&a_lds[(16 + lrow) * LDA + ks + quad * 8];
      for (int nt = 0; nt < 4; ++nt) {
        short8 b = pack8(w0 + (n0 + nt * 16 + lrow) * D_DIM + ks + quad * 8);
        acc[0][nt] = __builtin_amdgcn_mfma_f32_16x16x32_bf16(a0, b, acc[0][nt], 0, 0, 0);
        acc[1][nt] = __builtin_amdgcn_mfma_f32_16x16x32_bf16(a1, b, acc[1][nt], 0, 0, 0);
      }
    }
    for (int mt = 0; mt < 2; ++mt)
      for (int nt = 0; nt < 4; ++nt)
        for (int rr = 0; rr < 4; ++rr) {
          int row = mt * 16 + quad * 4 + rr;
          int col = n0 + nt * 16 + lrow;
          float v = acc[mt][nt][rr] + b0[col];
          t_lds[row * LDT + col] = f32_to_bf16(fmaxf(v, 0.0f));
        }
  }
  __syncthreads();

  // phase 2: y = t @ w1^T + b1; wave covers cols [wave*32, wave*32+32)
  {
    const int n0 = wave * 32;
    f32x4 acc[2][2] = {};
    for (int ks = 0; ks < 256; ks += 32) {
      short8 a0 = *(const short8*)&t_lds[lrow * LDT + ks + quad * 8];
      short8 a1 = *(const short8*)&t_lds[(16 + lrow) * LDT + ks + quad * 8];
      for (int nt = 0; nt < 2; ++nt) {
        short8 b = pack8(w1 + (n0 + nt * 16 + lrow) * 2 * D_DIM + ks + quad * 8);
        acc[0][nt] = __builtin_amdgcn_mfma_f32_16x16x32_bf16(a0, b, acc[0][nt], 0, 0, 0);
        acc[1][nt] = __builtin_amdgcn_mfma_f32_16x16x32_bf16(a1, b, acc[1][nt], 0, 0, 0);
      }
    }
    for (int mt = 0; mt < 2; ++mt)
      for (int nt = 0; nt < 2; ++nt)
        for (int rr = 0; rr < 4; ++rr) {
          int row = mt * 16 + quad * 4 + rr;
          int col = n0 + nt * 16 + lrow;
          y[(m0 + row) * D_DIM + col] = acc[mt][nt][rr] + b1[col];
        }
  }
}

// ---------------------------------------------------------------------------
extern "C" void kernel_launch(void* const* d_in, const int* in_sizes, int n_in,
                              void* d_out, int out_size, void* d_ws, size_t ws_size,
                              hipStream_t stream) {
  const int*   ei      = (const int*)d_in[0];
  const int*   et      = (const int*)d_in[1];
  const float* embed   = (const float*)d_in[2];
  const float* rel_emb = (const float*)d_in[3];
  const float* rmw0 = (const float*)d_in[4];  const float* rmb0 = (const float*)d_in[5];
  const float* rmw1 = (const float*)d_in[6];  const float* rmb1 = (const float*)d_in[7];
  const float* rmw2 = (const float*)d_in[8];  const float* rmb2 = (const float*)d_in[9];
  const float* rmw3 = (const float*)d_in[10]; const float* rmb3 = (const float*)d_in[11];
  const float* Ww   = (const float*)d_in[12]; const float* Wb   = (const float*)d_in[13];
  const float* mw0  = (const float*)d_in[14]; const float* mb0  = (const float*)d_in[15];
  const float* mw1  = (const float*)d_in[16]; const float* mb1  = (const float*)d_in[17];
  const float* eps  = (const float*)d_in[18];
  float* out = (float*)d_out;

  // workspace: W0, W1 (N x D each), gamma/beta (L x R x D each) ~= 102.6 MB
  float* W0    = (float*)d_ws;
  float* W1    = W0 + (size_t)N_NODES * D_DIM;
  float* gamma = W1 + (size_t)N_NODES * D_DIM;
  float* beta  = gamma + L_LAYERS * R_REL * D_DIM;

  gamma_beta_kernel<<<L_LAYERS * R_REL, 256, 0, stream>>>(
      rel_emb, rmw0, rmb0, rmw1, rmb1, rmw2, rmb2, rmw3, rmb3, gamma, beta);

  const int gN = N_NODES / 32;   // 3125
  const int gE = N_EDGES / 8;    // 80000

  // ---- layer 0: x = embed; xw->W0; out(d_out) = (1+eps)x + aggr; x1 -> W1
  xw_kernel<<<gN, 256, 0, stream>>>(embed, Ww, Wb, eps, W0, out);
  edge_kernel<<<gE, 256, 0, stream>>>(ei, et, W0, gamma, beta, out);
  mlp_kernel<<<gN, 256, 0, stream>>>(out, mw0, mb0, mw1, mb1, W1);

  // ---- layer 1: x = W1; xw->W0; out(d_out) = (1+eps)x + aggr; y -> d_out
  xw_kernel<<<gN, 256, 0, stream>>>(W1, Ww + D_DIM * D_DIM, Wb + D_DIM, eps + 1, W0, out);
  edge_kernel<<<gE, 256, 0, stream>>>(ei, et, W0, gamma + R_REL * D_DIM, beta + R_REL * D_DIM, out);
  mlp_kernel<<<gN, 256, 0, stream>>>(out, mw0 + 2 * D_DIM * D_DIM, mb0 + 2 * D_DIM,
                                     mw1 + 2 * D_DIM * D_DIM, mb1 + D_DIM, out);
}

// Round 2
// 658.865 us; speedup vs baseline: 3.9509x; 3.9509x over previous
//
#include <hip/hip_runtime.h>
#include <stdint.h>

#define N_NODES 100000
#define N_EDGES 640000
#define R_REL   64
#define D_DIM   128
#define L_LAYERS 2

#define SCAN_CHUNK 1024
#define NBLK_SCAN ((N_NODES + SCAN_CHUNK - 1) / SCAN_CHUNK)   // 98

typedef __attribute__((ext_vector_type(8))) short   short8;   // 8 bf16 (4 VGPRs) MFMA frag
typedef __attribute__((ext_vector_type(4))) unsigned short ushort4v;
typedef __attribute__((ext_vector_type(4))) float   f32x4;

__device__ __forceinline__ unsigned short f32_to_bf16(float f) {
  union { float f; uint32_t u; } v; v.f = f;
  uint32_t u = v.u;
  u += 0x7fffu + ((u >> 16) & 1u);   // RNE (finite inputs only)
  return (unsigned short)(u >> 16);
}

__device__ __forceinline__ short8 pack8(const float* __restrict__ p) {
  float4 u0 = *(const float4*)p;
  float4 u1 = *(const float4*)(p + 4);
  short8 r;
  r[0] = (short)f32_to_bf16(u0.x); r[1] = (short)f32_to_bf16(u0.y);
  r[2] = (short)f32_to_bf16(u0.z); r[3] = (short)f32_to_bf16(u0.w);
  r[4] = (short)f32_to_bf16(u1.x); r[5] = (short)f32_to_bf16(u1.y);
  r[6] = (short)f32_to_bf16(u1.z); r[7] = (short)f32_to_bf16(u1.w);
  return r;
}

// ---------------------------------------------------------------------------
// CSR build: histogram -> 3-kernel exclusive scan -> slot scatter
// ---------------------------------------------------------------------------
__global__ __launch_bounds__(256)
void hist_kernel(const int* __restrict__ ei, int* __restrict__ deg) {
  int idx = blockIdx.x * 256 + threadIdx.x;
  atomicAdd(&deg[ei[N_EDGES + idx]], 1);
}

__global__ __launch_bounds__(256)
void scan_part1(const int* __restrict__ deg, int* __restrict__ partial) {
  __shared__ int lds[256];
  const int b = blockIdx.x, t = threadIdx.x;
  const int base = b * SCAN_CHUNK + t * 4;
  int s = 0;
  for (int k = 0; k < 4; ++k) { int i = base + k; s += (i < N_NODES) ? deg[i] : 0; }
  lds[t] = s; __syncthreads();
  for (int off = 128; off > 0; off >>= 1) {
    if (t < off) lds[t] += lds[t + off];
    __syncthreads();
  }
  if (t == 0) partial[b] = lds[0];
}

__global__ __launch_bounds__(128)
void scan_part2(int* __restrict__ partial, int* __restrict__ blockoff) {
  __shared__ int lds[128];
  const int t = threadIdx.x;
  const int v = (t < NBLK_SCAN) ? partial[t] : 0;
  lds[t] = v; __syncthreads();
  for (int off = 1; off < 128; off <<= 1) {
    int add = (t >= off) ? lds[t - off] : 0;
    __syncthreads();
    lds[t] += add;
    __syncthreads();
  }
  if (t < NBLK_SCAN) blockoff[t] = lds[t] - v;   // exclusive
}

__global__ __launch_bounds__(256)
void scan_part3(const int* __restrict__ deg, const int* __restrict__ blockoff,
                int* __restrict__ rowptr, int* __restrict__ cursor) {
  __shared__ int lds[256];
  const int b = blockIdx.x, t = threadIdx.x;
  const int base = b * SCAN_CHUNK + t * 4;
  int v[4]; int s = 0;
  for (int k = 0; k < 4; ++k) {
    int i = base + k;
    v[k] = (i < N_NODES) ? deg[i] : 0;
    s += v[k];
  }
  lds[t] = s; __syncthreads();
  for (int off = 1; off < 256; off <<= 1) {
    int add = (t >= off) ? lds[t - off] : 0;
    __syncthreads();
    lds[t] += add;
    __syncthreads();
  }
  int excl = lds[t] - s + blockoff[b];
  for (int k = 0; k < 4; ++k) {
    int i = base + k;
    if (i < N_NODES) { rowptr[i] = excl; cursor[i] = excl; excl += v[k]; }
  }
  if (b == 0 && t == 0) rowptr[N_NODES] = N_EDGES;
}

__global__ __launch_bounds__(256)
void scatter_kernel(const int* __restrict__ ei, const int* __restrict__ et,
                    int* __restrict__ cursor, int2* __restrict__ edges2) {
  int idx = blockIdx.x * 256 + threadIdx.x;
  int dst = ei[N_EDGES + idx];
  int slot = atomicAdd(&cursor[dst], 1);
  edges2[slot] = make_int2(ei[idx], et[idx]);
}

// ---------------------------------------------------------------------------
// Kernel A: gamma/beta for both layers. grid = L*R blocks x 256 threads.
// ---------------------------------------------------------------------------
__global__ __launch_bounds__(256)
void gamma_beta_kernel(const float* __restrict__ rel_emb,
                       const float* __restrict__ rmw0, const float* __restrict__ rmb0,
                       const float* __restrict__ rmw1, const float* __restrict__ rmb1,
                       const float* __restrict__ rmw2, const float* __restrict__ rmb2,
                       const float* __restrict__ rmw3, const float* __restrict__ rmb3,
                       float* __restrict__ gamma, float* __restrict__ beta) {
  __shared__ float bufA[2 * D_DIM];
  __shared__ float bufB[2 * D_DIM];
  const int l = blockIdx.x >> 6;
  const int r = blockIdx.x & 63;
  const int j = threadIdx.x;   // 0..255

  if (j < D_DIM) bufA[j] = rel_emb[(l * R_REL + r) * D_DIM + j];
  __syncthreads();

  {
    const float* w = rmw0 + ((size_t)l * 2 * D_DIM + j) * D_DIM;
    float s = rmb0[l * 2 * D_DIM + j];
    for (int k = 0; k < D_DIM; k += 4) {
      float4 wv = *(const float4*)(w + k);
      s += wv.x * bufA[k] + wv.y * bufA[k + 1] + wv.z * bufA[k + 2] + wv.w * bufA[k + 3];
    }
    bufB[j] = fmaxf(s, 0.0f);
  }
  __syncthreads();
  {
    const float* w = rmw1 + ((size_t)l * 2 * D_DIM + j) * 2 * D_DIM;
    float s = rmb1[l * 2 * D_DIM + j];
    for (int k = 0; k < 2 * D_DIM; k += 4) {
      float4 wv = *(const float4*)(w + k);
      s += wv.x * bufB[k] + wv.y * bufB[k + 1] + wv.z * bufB[k + 2] + wv.w * bufB[k + 3];
    }
    __syncthreads();
    bufA[j] = fmaxf(s, 0.0f);
  }
  __syncthreads();
  {
    const float* w = rmw2 + ((size_t)l * 2 * D_DIM + j) * 2 * D_DIM;
    float s = rmb2[l * 2 * D_DIM + j];
    for (int k = 0; k < 2 * D_DIM; k += 4) {
      float4 wv = *(const float4*)(w + k);
      s += wv.x * bufA[k] + wv.y * bufA[k + 1] + wv.z * bufA[k + 2] + wv.w * bufA[k + 3];
    }
    __syncthreads();
    bufB[j] = fmaxf(s, 0.0f);
  }
  __syncthreads();
  {
    const float* w = rmw3 + ((size_t)l * 2 * D_DIM + j) * 2 * D_DIM;
    float s = rmb3[l * 2 * D_DIM + j];
    for (int k = 0; k < 2 * D_DIM; k += 4) {
      float4 wv = *(const float4*)(w + k);
      s += wv.x * bufB[k] + wv.y * bufB[k + 1] + wv.z * bufB[k + 2] + wv.w * bufB[k + 3];
    }
    if (j < D_DIM) gamma[(l * R_REL + r) * D_DIM + j] = s;
    else           beta[(l * R_REL + r) * D_DIM + (j - D_DIM)] = s;
  }
}

// ---------------------------------------------------------------------------
// Kernel B: xw = x @ Ww^T + Wb  (N x 128).
// ---------------------------------------------------------------------------
#define LDA 136   // 128 + 8 pad (bf16 elems)

__global__ __launch_bounds__(256)
void xw_kernel(const float* __restrict__ x,
               const float* __restrict__ Ww,   // 128x128 layer slice
               const float* __restrict__ Wb,   // 128
               float* __restrict__ xw) {
  __shared__ unsigned short a_lds[32 * LDA];
  const int tid = threadIdx.x;
  const int m0 = blockIdx.x * 32;

  for (int i = tid; i < 1024; i += 256) {
    int row = i >> 5, ch = i & 31;
    float4 v = *(const float4*)&x[(m0 + row) * D_DIM + ch * 4];
    ushort4v s;
    s[0] = f32_to_bf16(v.x); s[1] = f32_to_bf16(v.y);
    s[2] = f32_to_bf16(v.z); s[3] = f32_to_bf16(v.w);
    *(ushort4v*)&a_lds[row * LDA + ch * 4] = s;
  }
  __syncthreads();

  const int wave = tid >> 6, lane = tid & 63;
  const int lrow = lane & 15, quad = lane >> 4;
  const int n0 = wave * 32;

  f32x4 acc[2][2] = {};
  for (int ks = 0; ks < 128; ks += 32) {
    short8 a0 = *(const short8*)&a_lds[lrow * LDA + ks + quad * 8];
    short8 a1 = *(const short8*)&a_lds[(16 + lrow) * LDA + ks + quad * 8];
    short8 b0 = pack8(Ww + (n0 + lrow) * D_DIM + ks + quad * 8);
    short8 b1 = pack8(Ww + (n0 + 16 + lrow) * D_DIM + ks + quad * 8);
    acc[0][0] = __builtin_amdgcn_mfma_f32_16x16x32_bf16(a0, b0, acc[0][0], 0, 0, 0);
    acc[0][1] = __builtin_amdgcn_mfma_f32_16x16x32_bf16(a0, b1, acc[0][1], 0, 0, 0);
    acc[1][0] = __builtin_amdgcn_mfma_f32_16x16x32_bf16(a1, b0, acc[1][0], 0, 0, 0);
    acc[1][1] = __builtin_amdgcn_mfma_f32_16x16x32_bf16(a1, b1, acc[1][1], 0, 0, 0);
  }

  for (int mt = 0; mt < 2; ++mt)
    for (int nt = 0; nt < 2; ++nt)
      for (int rr = 0; rr < 4; ++rr) {
        int row = mt * 16 + quad * 4 + rr;
        int col = n0 + nt * 16 + lrow;
        xw[(m0 + row) * D_DIM + col] = acc[mt][nt][rr] + Wb[col];
      }
}

// ---------------------------------------------------------------------------
// Kernel C: CSR gather. One wave per dst node, float2 per lane.
// out[n] = (1+eps)*x[n] + sum_{e in CSR row n} gamma[t_e]*xw[src_e] + beta[t_e]
// ---------------------------------------------------------------------------
__global__ __launch_bounds__(256)
void gather_kernel(const int2* __restrict__ edges2, const int* __restrict__ rowptr,
                   const float* __restrict__ x, const float* __restrict__ xw,
                   const float* __restrict__ gamma, const float* __restrict__ beta,
                   const float* __restrict__ eps, float* __restrict__ out) {
  const int node = blockIdx.x * 4 + (threadIdx.x >> 6);
  const int lane = threadIdx.x & 63;
  const int c = lane * 2;
  const int beg = rowptr[node];
  const int end = rowptr[node + 1];
  float ax = 0.0f, ay = 0.0f;
  int i = beg;
  for (; i + 2 <= end; i += 2) {
    int2 e0 = edges2[i];
    int2 e1 = edges2[i + 1];
    float2 x0 = *(const float2*)&xw[(size_t)e0.x * D_DIM + c];
    float2 g0 = *(const float2*)&gamma[e0.y * D_DIM + c];
    float2 b0 = *(const float2*)&beta[e0.y * D_DIM + c];
    float2 x1 = *(const float2*)&xw[(size_t)e1.x * D_DIM + c];
    float2 g1 = *(const float2*)&gamma[e1.y * D_DIM + c];
    float2 b1 = *(const float2*)&beta[e1.y * D_DIM + c];
    ax += g0.x * x0.x + b0.x; ay += g0.y * x0.y + b0.y;
    ax += g1.x * x1.x + b1.x; ay += g1.y * x1.y + b1.y;
  }
  if (i < end) {
    int2 e0 = edges2[i];
    float2 x0 = *(const float2*)&xw[(size_t)e0.x * D_DIM + c];
    float2 g0 = *(const float2*)&gamma[e0.y * D_DIM + c];
    float2 b0 = *(const float2*)&beta[e0.y * D_DIM + c];
    ax += g0.x * x0.x + b0.x; ay += g0.y * x0.y + b0.y;
  }
  const float e1v = 1.0f + eps[0];
  float2 xo = *(const float2*)&x[(size_t)node * D_DIM + c];
  float2 o;
  o.x = e1v * xo.x + ax;
  o.y = e1v * xo.y + ay;
  *(float2*)&out[(size_t)node * D_DIM + c] = o;
}

// ---------------------------------------------------------------------------
// Kernel D: fused node MLP. y = relu(in @ w0^T + b0) @ w1^T + b1.
// ---------------------------------------------------------------------------
#define LDT 264   // 256 + 8 pad

__global__ __launch_bounds__(256)
void mlp_kernel(const float* __restrict__ in,
                const float* __restrict__ w0, const float* __restrict__ b0,  // 256x128, 256
                const float* __restrict__ w1, const float* __restrict__ b1,  // 128x256, 128
                float* __restrict__ y) {
  __shared__ unsigned short a_lds[32 * LDA];
  __shared__ unsigned short t_lds[32 * LDT];
  const int tid = threadIdx.x;
  const int m0 = blockIdx.x * 32;

  for (int i = tid; i < 1024; i += 256) {
    int row = i >> 5, ch = i & 31;
    float4 v = *(const float4*)&in[(m0 + row) * D_DIM + ch * 4];
    ushort4v s;
    s[0] = f32_to_bf16(v.x); s[1] = f32_to_bf16(v.y);
    s[2] = f32_to_bf16(v.z); s[3] = f32_to_bf16(v.w);
    *(ushort4v*)&a_lds[row * LDA + ch * 4] = s;
  }
  __syncthreads();

  const int wave = tid >> 6, lane = tid & 63;
  const int lrow = lane & 15, quad = lane >> 4;

  {
    const int n0 = wave * 64;
    f32x4 acc[2][4] = {};
    for (int ks = 0; ks < 128; ks += 32) {
      short8 a0 = *(const short8*)&a_lds[lrow * LDA + ks + quad * 8];
      short8 a1 = *(const short8*)&a_lds[(16 + lrow) * LDA + ks + quad * 8];
      for (int nt = 0; nt < 4; ++nt) {
        short8 b = pack8(w0 + (n0 + nt * 16 + lrow) * D_DIM + ks + quad * 8);
        acc[0][nt] = __builtin_amdgcn_mfma_f32_16x16x32_bf16(a0, b, acc[0][nt], 0, 0, 0);
        acc[1][nt] = __builtin_amdgcn_mfma_f32_16x16x32_bf16(a1, b, acc[1][nt], 0, 0, 0);
      }
    }
    for (int mt = 0; mt < 2; ++mt)
      for (int nt = 0; nt < 4; ++nt)
        for (int rr = 0; rr < 4; ++rr) {
          int row = mt * 16 + quad * 4 + rr;
          int col = n0 + nt * 16 + lrow;
          float v = acc[mt][nt][rr] + b0[col];
          t_lds[row * LDT + col] = f32_to_bf16(fmaxf(v, 0.0f));
        }
  }
  __syncthreads();

  {
    const int n0 = wave * 32;
    f32x4 acc[2][2] = {};
    for (int ks = 0; ks < 256; ks += 32) {
      short8 a0 = *(const short8*)&t_lds[lrow * LDT + ks + quad * 8];
      short8 a1 = *(const short8*)&t_lds[(16 + lrow) * LDT + ks + quad * 8];
      for (int nt = 0; nt < 2; ++nt) {
        short8 b = pack8(w1 + (n0 + nt * 16 + lrow) * 2 * D_DIM + ks + quad * 8);
        acc[0][nt] = __builtin_amdgcn_mfma_f32_16x16x32_bf16(a0, b, acc[0][nt], 0, 0, 0);
        acc[1][nt] = __builtin_amdgcn_mfma_f32_16x16x32_bf16(a1, b, acc[1][nt], 0, 0, 0);
      }
    }
    for (int mt = 0; mt < 2; ++mt)
      for (int nt = 0; nt < 2; ++nt)
        for (int rr = 0; rr < 4; ++rr) {
          int row = mt * 16 + quad * 4 + rr;
          int col = n0 + nt * 16 + lrow;
          y[(m0 + row) * D_DIM + col] = acc[mt][nt][rr] + b1[col];
        }
  }
}

// ---------------------------------------------------------------------------
extern "C" void kernel_launch(void* const* d_in, const int* in_sizes, int n_in,
                              void* d_out, int out_size, void* d_ws, size_t ws_size,
                              hipStream_t stream) {
  const int*   ei      = (const int*)d_in[0];
  const int*   et      = (const int*)d_in[1];
  const float* embed   = (const float*)d_in[2];
  const float* rel_emb = (const float*)d_in[3];
  const float* rmw0 = (const float*)d_in[4];  const float* rmb0 = (const float*)d_in[5];
  const float* rmw1 = (const float*)d_in[6];  const float* rmb1 = (const float*)d_in[7];
  const float* rmw2 = (const float*)d_in[8];  const float* rmb2 = (const float*)d_in[9];
  const float* rmw3 = (const float*)d_in[10]; const float* rmb3 = (const float*)d_in[11];
  const float* Ww   = (const float*)d_in[12]; const float* Wb   = (const float*)d_in[13];
  const float* mw0  = (const float*)d_in[14]; const float* mb0  = (const float*)d_in[15];
  const float* mw1  = (const float*)d_in[16]; const float* mb1  = (const float*)d_in[17];
  const float* eps  = (const float*)d_in[18];
  float* out = (float*)d_out;

  // workspace layout
  float* W0    = (float*)d_ws;                            // N*D
  float* W1    = W0 + (size_t)N_NODES * D_DIM;            // N*D
  float* gamma = W1 + (size_t)N_NODES * D_DIM;            // L*R*D
  float* beta  = gamma + L_LAYERS * R_REL * D_DIM;        // L*R*D
  int*   deg     = (int*)(beta + L_LAYERS * R_REL * D_DIM);  // N
  int*   rowptr  = deg + N_NODES;                          // N+1
  int*   cursor  = rowptr + N_NODES + 1;                   // N
  int*   partial = cursor + N_NODES;                       // NBLK_SCAN
  int*   blockoff= partial + NBLK_SCAN;                    // NBLK_SCAN
  int2*  edges2  = (int2*)(blockoff + NBLK_SCAN + 1);      // E (8B each)

  // ---- CSR build (once; reused by both layers)
  hipMemsetAsync(deg, 0, N_NODES * sizeof(int), stream);
  hist_kernel<<<N_EDGES / 256, 256, 0, stream>>>(ei, deg);
  scan_part1<<<NBLK_SCAN, 256, 0, stream>>>(deg, partial);
  scan_part2<<<1, 128, 0, stream>>>(partial, blockoff);
  scan_part3<<<NBLK_SCAN, 256, 0, stream>>>(deg, blockoff, rowptr, cursor);
  scatter_kernel<<<N_EDGES / 256, 256, 0, stream>>>(ei, et, cursor, edges2);

  gamma_beta_kernel<<<L_LAYERS * R_REL, 256, 0, stream>>>(
      rel_emb, rmw0, rmb0, rmw1, rmb1, rmw2, rmb2, rmw3, rmb3, gamma, beta);

  const int gN = N_NODES / 32;        // 3125
  const int gG = N_NODES / 4;         // 25000 (4 nodes/block, 1 wave/node)

  // ---- layer 0
  xw_kernel<<<gN, 256, 0, stream>>>(embed, Ww, Wb, W0);
  gather_kernel<<<gG, 256, 0, stream>>>(edges2, rowptr, embed, W0, gamma, beta, eps, out);
  mlp_kernel<<<gN, 256, 0, stream>>>(out, mw0, mb0, mw1, mb1, W1);

  // ---- layer 1
  xw_kernel<<<gN, 256, 0, stream>>>(W1, Ww + D_DIM * D_DIM, Wb + D_DIM, W0);
  gather_kernel<<<gG, 256, 0, stream>>>(edges2, rowptr, W1, W0,
                                        gamma + R_REL * D_DIM, beta + R_REL * D_DIM,
                                        eps + 1, out);
  mlp_kernel<<<gN, 256, 0, stream>>>(out, mw0 + 2 * D_DIM * D_DIM, mb0 + 2 * D_DIM,
                                     mw1 + 2 * D_DIM * D_DIM, mb1 + D_DIM, out);
}

// Round 3
// 563.179 us; speedup vs baseline: 4.6222x; 1.1699x over previous
//
#include <hip/hip_runtime.h>
#include <stdint.h>

#define N_NODES 100000
#define N_EDGES 640000
#define R_REL   64
#define D_DIM   128
#define L_LAYERS 2

#define SCAN_CHUNK 1024
#define NBLK_SCAN ((N_NODES + SCAN_CHUNK - 1) / SCAN_CHUNK)   // 98

typedef __attribute__((ext_vector_type(8))) short   short8;   // 8 bf16 (4 VGPRs) MFMA frag
typedef __attribute__((ext_vector_type(4))) unsigned short ushort4v;
typedef __attribute__((ext_vector_type(4))) float   f32x4;

__device__ __forceinline__ unsigned short f32_to_bf16(float f) {
  union { float f; uint32_t u; } v; v.f = f;
  uint32_t u = v.u;
  u += 0x7fffu + ((u >> 16) & 1u);   // RNE (finite inputs only)
  return (unsigned short)(u >> 16);
}

// ---------------------------------------------------------------------------
// Weight pre-conversion: f32 -> bf16, row-major, both layers. One-shot.
// ---------------------------------------------------------------------------
__global__ __launch_bounds__(256)
void wconv_kernel(const float* __restrict__ Ww, const float* __restrict__ mw0,
                  const float* __restrict__ mw1,
                  unsigned short* __restrict__ Wwb, unsigned short* __restrict__ mw0b,
                  unsigned short* __restrict__ mw1b) {
  int i = blockIdx.x * 256 + threadIdx.x;            // 0 .. 65535
  if (i < L_LAYERS * D_DIM * D_DIM)     Wwb[i]  = f32_to_bf16(Ww[i]);
  if (i < L_LAYERS * 2 * D_DIM * D_DIM) mw0b[i] = f32_to_bf16(mw0[i]);
  if (i < L_LAYERS * 2 * D_DIM * D_DIM) mw1b[i] = f32_to_bf16(mw1[i]);
}

// ---------------------------------------------------------------------------
// CSR build: histogram -> 3-kernel exclusive scan -> slot scatter
// ---------------------------------------------------------------------------
__global__ __launch_bounds__(256)
void hist_kernel(const int* __restrict__ ei, int* __restrict__ deg) {
  int idx = blockIdx.x * 256 + threadIdx.x;
  atomicAdd(&deg[ei[N_EDGES + idx]], 1);
}

__global__ __launch_bounds__(256)
void scan_part1(const int* __restrict__ deg, int* __restrict__ partial) {
  __shared__ int lds[256];
  const int b = blockIdx.x, t = threadIdx.x;
  const int base = b * SCAN_CHUNK + t * 4;
  int s = 0;
  for (int k = 0; k < 4; ++k) { int i = base + k; s += (i < N_NODES) ? deg[i] : 0; }
  lds[t] = s; __syncthreads();
  for (int off = 128; off > 0; off >>= 1) {
    if (t < off) lds[t] += lds[t + off];
    __syncthreads();
  }
  if (t == 0) partial[b] = lds[0];
}

__global__ __launch_bounds__(128)
void scan_part2(int* __restrict__ partial, int* __restrict__ blockoff) {
  __shared__ int lds[128];
  const int t = threadIdx.x;
  const int v = (t < NBLK_SCAN) ? partial[t] : 0;
  lds[t] = v; __syncthreads();
  for (int off = 1; off < 128; off <<= 1) {
    int add = (t >= off) ? lds[t - off] : 0;
    __syncthreads();
    lds[t] += add;
    __syncthreads();
  }
  if (t < NBLK_SCAN) blockoff[t] = lds[t] - v;   // exclusive
}

__global__ __launch_bounds__(256)
void scan_part3(const int* __restrict__ deg, const int* __restrict__ blockoff,
                int* __restrict__ rowptr, int* __restrict__ cursor) {
  __shared__ int lds[256];
  const int b = blockIdx.x, t = threadIdx.x;
  const int base = b * SCAN_CHUNK + t * 4;
  int v[4]; int s = 0;
  for (int k = 0; k < 4; ++k) {
    int i = base + k;
    v[k] = (i < N_NODES) ? deg[i] : 0;
    s += v[k];
  }
  lds[t] = s; __syncthreads();
  for (int off = 1; off < 256; off <<= 1) {
    int add = (t >= off) ? lds[t - off] : 0;
    __syncthreads();
    lds[t] += add;
    __syncthreads();
  }
  int excl = lds[t] - s + blockoff[b];
  for (int k = 0; k < 4; ++k) {
    int i = base + k;
    if (i < N_NODES) { rowptr[i] = excl; cursor[i] = excl; excl += v[k]; }
  }
  if (b == 0 && t == 0) rowptr[N_NODES] = N_EDGES;
}

__global__ __launch_bounds__(256)
void scatter_kernel(const int* __restrict__ ei, const int* __restrict__ et,
                    int* __restrict__ cursor, int2* __restrict__ edges2) {
  int idx = blockIdx.x * 256 + threadIdx.x;
  int dst = ei[N_EDGES + idx];
  int slot = atomicAdd(&cursor[dst], 1);
  edges2[slot] = make_int2(ei[idx], et[idx]);
}

// ---------------------------------------------------------------------------
// gamma/beta for both layers. grid = L*R blocks x 256 threads. All f32 exact.
// ---------------------------------------------------------------------------
__global__ __launch_bounds__(256)
void gamma_beta_kernel(const float* __restrict__ rel_emb,
                       const float* __restrict__ rmw0, const float* __restrict__ rmb0,
                       const float* __restrict__ rmw1, const float* __restrict__ rmb1,
                       const float* __restrict__ rmw2, const float* __restrict__ rmb2,
                       const float* __restrict__ rmw3, const float* __restrict__ rmb3,
                       float* __restrict__ gamma, float* __restrict__ beta) {
  __shared__ float bufA[2 * D_DIM];
  __shared__ float bufB[2 * D_DIM];
  const int l = blockIdx.x >> 6;
  const int r = blockIdx.x & 63;
  const int j = threadIdx.x;   // 0..255

  if (j < D_DIM) bufA[j] = rel_emb[(l * R_REL + r) * D_DIM + j];
  __syncthreads();

  {
    const float* w = rmw0 + ((size_t)l * 2 * D_DIM + j) * D_DIM;
    float s = rmb0[l * 2 * D_DIM + j];
    for (int k = 0; k < D_DIM; k += 4) {
      float4 wv = *(const float4*)(w + k);
      s += wv.x * bufA[k] + wv.y * bufA[k + 1] + wv.z * bufA[k + 2] + wv.w * bufA[k + 3];
    }
    bufB[j] = fmaxf(s, 0.0f);
  }
  __syncthreads();
  {
    const float* w = rmw1 + ((size_t)l * 2 * D_DIM + j) * 2 * D_DIM;
    float s = rmb1[l * 2 * D_DIM + j];
    for (int k = 0; k < 2 * D_DIM; k += 4) {
      float4 wv = *(const float4*)(w + k);
      s += wv.x * bufB[k] + wv.y * bufB[k + 1] + wv.z * bufB[k + 2] + wv.w * bufB[k + 3];
    }
    __syncthreads();
    bufA[j] = fmaxf(s, 0.0f);
  }
  __syncthreads();
  {
    const float* w = rmw2 + ((size_t)l * 2 * D_DIM + j) * 2 * D_DIM;
    float s = rmb2[l * 2 * D_DIM + j];
    for (int k = 0; k < 2 * D_DIM; k += 4) {
      float4 wv = *(const float4*)(w + k);
      s += wv.x * bufA[k] + wv.y * bufA[k + 1] + wv.z * bufA[k + 2] + wv.w * bufA[k + 3];
    }
    __syncthreads();
    bufB[j] = fmaxf(s, 0.0f);
  }
  __syncthreads();
  {
    const float* w = rmw3 + ((size_t)l * 2 * D_DIM + j) * 2 * D_DIM;
    float s = rmb3[l * 2 * D_DIM + j];
    for (int k = 0; k < 2 * D_DIM; k += 4) {
      float4 wv = *(const float4*)(w + k);
      s += wv.x * bufB[k] + wv.y * bufB[k + 1] + wv.z * bufB[k + 2] + wv.w * bufB[k + 3];
    }
    if (j < D_DIM) gamma[(l * R_REL + r) * D_DIM + j] = s;
    else           beta[(l * R_REL + r) * D_DIM + (j - D_DIM)] = s;
  }
}

// ---------------------------------------------------------------------------
// xw = x @ Ww^T + Wb  (N x 128). bf16 weights, direct short8 loads.
// ---------------------------------------------------------------------------
#define LDA 136   // 128 + 8 pad (bf16 elems)
#define LDT 264   // 256 + 8 pad

__global__ __launch_bounds__(256)
void xw_kernel(const float* __restrict__ x,
               const unsigned short* __restrict__ Wwb,  // 128x128 bf16 layer slice
               const float* __restrict__ Wb,            // 128
               float* __restrict__ xw) {
  __shared__ unsigned short a_lds[32 * LDA];
  const int tid = threadIdx.x;
  const int m0 = blockIdx.x * 32;

  for (int i = tid; i < 1024; i += 256) {
    int row = i >> 5, ch = i & 31;
    float4 v = *(const float4*)&x[(m0 + row) * D_DIM + ch * 4];
    ushort4v s;
    s[0] = f32_to_bf16(v.x); s[1] = f32_to_bf16(v.y);
    s[2] = f32_to_bf16(v.z); s[3] = f32_to_bf16(v.w);
    *(ushort4v*)&a_lds[row * LDA + ch * 4] = s;
  }
  __syncthreads();

  const int wave = tid >> 6, lane = tid & 63;
  const int lrow = lane & 15, quad = lane >> 4;
  const int n0 = wave * 32;

  f32x4 acc[2][2] = {};
  for (int ks = 0; ks < 128; ks += 32) {
    short8 a0 = *(const short8*)&a_lds[lrow * LDA + ks + quad * 8];
    short8 a1 = *(const short8*)&a_lds[(16 + lrow) * LDA + ks + quad * 8];
    short8 b0 = *(const short8*)&Wwb[(n0 + lrow) * D_DIM + ks + quad * 8];
    short8 b1 = *(const short8*)&Wwb[(n0 + 16 + lrow) * D_DIM + ks + quad * 8];
    acc[0][0] = __builtin_amdgcn_mfma_f32_16x16x32_bf16(a0, b0, acc[0][0], 0, 0, 0);
    acc[0][1] = __builtin_amdgcn_mfma_f32_16x16x32_bf16(a0, b1, acc[0][1], 0, 0, 0);
    acc[1][0] = __builtin_amdgcn_mfma_f32_16x16x32_bf16(a1, b0, acc[1][0], 0, 0, 0);
    acc[1][1] = __builtin_amdgcn_mfma_f32_16x16x32_bf16(a1, b1, acc[1][1], 0, 0, 0);
  }

  for (int mt = 0; mt < 2; ++mt)
    for (int nt = 0; nt < 2; ++nt)
      for (int rr = 0; rr < 4; ++rr) {
        int row = mt * 16 + quad * 4 + rr;
        int col = n0 + nt * 16 + lrow;
        xw[(m0 + row) * D_DIM + col] = acc[mt][nt][rr] + Wb[col];
      }
}

// ---------------------------------------------------------------------------
// Fused gather + node MLP. Block = 32 nodes, 4 waves.
// Phase A: wave w gathers nodes [m0+8w, m0+8w+8): aggr over CSR row, then
//          o = (1+eps)*x + aggr -> bf16 -> A-tile in LDS.
// Phase B: t = relu(o @ w0^T + b0) -> LDS (overlaid on A-tile).
// Phase C: y = t @ w1^T + b1 -> global.
// ---------------------------------------------------------------------------
__global__ __launch_bounds__(256)
void gather_mlp_kernel(const int2* __restrict__ edges2, const int* __restrict__ rowptr,
                       const float* __restrict__ x, const float* __restrict__ xw,
                       const float* __restrict__ gamma, const float* __restrict__ beta,
                       const float* __restrict__ eps,
                       const unsigned short* __restrict__ w0b, const float* __restrict__ b0,
                       const unsigned short* __restrict__ w1b, const float* __restrict__ b1,
                       float* __restrict__ y) {
  __shared__ unsigned short u_lds[32 * LDT];   // 16896 B, phases overlay
  unsigned short* a_lds = u_lds;               // stride LDA (phase A/B read)
  unsigned short* t_lds = u_lds;               // stride LDT (phase B write / C read)

  const int tid = threadIdx.x;
  const int m0 = blockIdx.x * 32;
  const int wave = tid >> 6, lane = tid & 63;
  const float e1v = 1.0f + eps[0];

  // ---- phase A: gather 8 nodes per wave
  for (int i = 0; i < 8; ++i) {
    const int row = wave * 8 + i;
    const int node = m0 + row;
    const int c = lane * 2;
    const int beg = rowptr[node];
    const int end = rowptr[node + 1];
    float ax = 0.0f, ay = 0.0f;
    int e = beg;
    for (; e + 2 <= end; e += 2) {
      int2 e0 = edges2[e];
      int2 e1 = edges2[e + 1];
      float2 x0 = *(const float2*)&xw[(size_t)e0.x * D_DIM + c];
      float2 g0 = *(const float2*)&gamma[e0.y * D_DIM + c];
      float2 bb0 = *(const float2*)&beta[e0.y * D_DIM + c];
      float2 x1 = *(const float2*)&xw[(size_t)e1.x * D_DIM + c];
      float2 g1 = *(const float2*)&gamma[e1.y * D_DIM + c];
      float2 bb1 = *(const float2*)&beta[e1.y * D_DIM + c];
      ax += g0.x * x0.x + bb0.x; ay += g0.y * x0.y + bb0.y;
      ax += g1.x * x1.x + bb1.x; ay += g1.y * x1.y + bb1.y;
    }
    if (e < end) {
      int2 e0 = edges2[e];
      float2 x0 = *(const float2*)&xw[(size_t)e0.x * D_DIM + c];
      float2 g0 = *(const float2*)&gamma[e0.y * D_DIM + c];
      float2 bb0 = *(const float2*)&beta[e0.y * D_DIM + c];
      ax += g0.x * x0.x + bb0.x; ay += g0.y * x0.y + bb0.y;
    }
    float2 xo = *(const float2*)&x[(size_t)node * D_DIM + c];
    float ox = e1v * xo.x + ax;
    float oy = e1v * xo.y + ay;
    uint32_t packed = (uint32_t)f32_to_bf16(ox) | ((uint32_t)f32_to_bf16(oy) << 16);
    *(uint32_t*)&a_lds[row * LDA + c] = packed;
  }
  __syncthreads();

  const int lrow = lane & 15, quad = lane >> 4;

  // ---- phase B: t = relu(o @ w0^T + b0); wave covers cols [wave*64, +64)
  {
    const int n0 = wave * 64;
    f32x4 acc[2][4] = {};
    for (int ks = 0; ks < 128; ks += 32) {
      short8 a0 = *(const short8*)&a_lds[lrow * LDA + ks + quad * 8];
      short8 a1 = *(const short8*)&a_lds[(16 + lrow) * LDA + ks + quad * 8];
      for (int nt = 0; nt < 4; ++nt) {
        short8 b = *(const short8*)&w0b[(n0 + nt * 16 + lrow) * D_DIM + ks + quad * 8];
        acc[0][nt] = __builtin_amdgcn_mfma_f32_16x16x32_bf16(a0, b, acc[0][nt], 0, 0, 0);
        acc[1][nt] = __builtin_amdgcn_mfma_f32_16x16x32_bf16(a1, b, acc[1][nt], 0, 0, 0);
      }
    }
    __syncthreads();   // all waves done reading A-tile before overlay write
    for (int mt = 0; mt < 2; ++mt)
      for (int nt = 0; nt < 4; ++nt)
        for (int rr = 0; rr < 4; ++rr) {
          int row = mt * 16 + quad * 4 + rr;
          int col = n0 + nt * 16 + lrow;
          float v = acc[mt][nt][rr] + b0[col];
          t_lds[row * LDT + col] = f32_to_bf16(fmaxf(v, 0.0f));
        }
  }
  __syncthreads();

  // ---- phase C: y = t @ w1^T + b1; wave covers cols [wave*32, +32)
  {
    const int n0 = wave * 32;
    f32x4 acc[2][2] = {};
    for (int ks = 0; ks < 256; ks += 32) {
      short8 a0 = *(const short8*)&t_lds[lrow * LDT + ks + quad * 8];
      short8 a1 = *(const short8*)&t_lds[(16 + lrow) * LDT + ks + quad * 8];
      for (int nt = 0; nt < 2; ++nt) {
        short8 b = *(const short8*)&w1b[(n0 + nt * 16 + lrow) * 2 * D_DIM + ks + quad * 8];
        acc[0][nt] = __builtin_amdgcn_mfma_f32_16x16x32_bf16(a0, b, acc[0][nt], 0, 0, 0);
        acc[1][nt] = __builtin_amdgcn_mfma_f32_16x16x32_bf16(a1, b, acc[1][nt], 0, 0, 0);
      }
    }
    for (int mt = 0; mt < 2; ++mt)
      for (int nt = 0; nt < 2; ++nt)
        for (int rr = 0; rr < 4; ++rr) {
          int row = mt * 16 + quad * 4 + rr;
          int col = n0 + nt * 16 + lrow;
          y[(size_t)(m0 + row) * D_DIM + col] = acc[mt][nt][rr] + b1[col];
        }
  }
}

// ---------------------------------------------------------------------------
extern "C" void kernel_launch(void* const* d_in, const int* in_sizes, int n_in,
                              void* d_out, int out_size, void* d_ws, size_t ws_size,
                              hipStream_t stream) {
  const int*   ei      = (const int*)d_in[0];
  const int*   et      = (const int*)d_in[1];
  const float* embed   = (const float*)d_in[2];
  const float* rel_emb = (const float*)d_in[3];
  const float* rmw0 = (const float*)d_in[4];  const float* rmb0 = (const float*)d_in[5];
  const float* rmw1 = (const float*)d_in[6];  const float* rmb1 = (const float*)d_in[7];
  const float* rmw2 = (const float*)d_in[8];  const float* rmb2 = (const float*)d_in[9];
  const float* rmw3 = (const float*)d_in[10]; const float* rmb3 = (const float*)d_in[11];
  const float* Ww   = (const float*)d_in[12]; const float* Wb   = (const float*)d_in[13];
  const float* mw0  = (const float*)d_in[14]; const float* mb0  = (const float*)d_in[15];
  const float* mw1  = (const float*)d_in[16]; const float* mb1  = (const float*)d_in[17];
  const float* eps  = (const float*)d_in[18];
  float* out = (float*)d_out;

  // workspace layout
  float* W0    = (float*)d_ws;                            // N*D f32
  float* W1    = W0 + (size_t)N_NODES * D_DIM;            // N*D f32
  float* gamma = W1 + (size_t)N_NODES * D_DIM;            // L*R*D f32
  float* beta  = gamma + L_LAYERS * R_REL * D_DIM;        // L*R*D f32
  int*   deg     = (int*)(beta + L_LAYERS * R_REL * D_DIM);  // N
  int*   rowptr  = deg + N_NODES;                          // N+1
  int*   cursor  = rowptr + N_NODES + 1;                   // N
  int*   partial = cursor + N_NODES;                       // NBLK_SCAN
  int*   blockoff= partial + NBLK_SCAN;                    // NBLK_SCAN
  int2*  edges2  = (int2*)(blockoff + NBLK_SCAN + 1);      // E int2
  unsigned short* Wwb  = (unsigned short*)(edges2 + N_EDGES);          // L*128*128 bf16
  unsigned short* mw0b = Wwb + L_LAYERS * D_DIM * D_DIM;               // L*256*128 bf16
  unsigned short* mw1b = mw0b + L_LAYERS * 2 * D_DIM * D_DIM;          // L*128*256 bf16

  // ---- one-shot preprocessing
  hipMemsetAsync(deg, 0, N_NODES * sizeof(int), stream);
  hist_kernel<<<N_EDGES / 256, 256, 0, stream>>>(ei, deg);
  scan_part1<<<NBLK_SCAN, 256, 0, stream>>>(deg, partial);
  scan_part2<<<1, 128, 0, stream>>>(partial, blockoff);
  scan_part3<<<NBLK_SCAN, 256, 0, stream>>>(deg, blockoff, rowptr, cursor);
  scatter_kernel<<<N_EDGES / 256, 256, 0, stream>>>(ei, et, cursor, edges2);
  wconv_kernel<<<256, 256, 0, stream>>>(Ww, mw0, mw1, Wwb, mw0b, mw1b);
  gamma_beta_kernel<<<L_LAYERS * R_REL, 256, 0, stream>>>(
      rel_emb, rmw0, rmb0, rmw1, rmb1, rmw2, rmb2, rmw3, rmb3, gamma, beta);

  const int gN = N_NODES / 32;        // 3125

  // ---- layer 0: x = embed -> xw in W0 -> fused gather+mlp -> W1
  xw_kernel<<<gN, 256, 0, stream>>>(embed, Wwb, Wb, W0);
  gather_mlp_kernel<<<gN, 256, 0, stream>>>(edges2, rowptr, embed, W0, gamma, beta, eps,
                                            mw0b, mb0, mw1b, mb1, W1);

  // ---- layer 1: x = W1 -> xw in W0 -> fused gather+mlp -> d_out
  xw_kernel<<<gN, 256, 0, stream>>>(W1, Wwb + D_DIM * D_DIM, Wb + D_DIM, W0);
  gather_mlp_kernel<<<gN, 256, 0, stream>>>(edges2, rowptr, W1, W0,
                                            gamma + R_REL * D_DIM, beta + R_REL * D_DIM,
                                            eps + 1,
                                            mw0b + 2 * D_DIM * D_DIM, mb0 + 2 * D_DIM,
                                            mw1b + 2 * D_DIM * D_DIM, mb1 + D_DIM, out);
}

// Round 4
// 466.140 us; speedup vs baseline: 5.5844x; 1.2082x over previous
//
#include <hip/hip_runtime.h>
#include <stdint.h>

#define N_NODES 100000
#define N_EDGES 640000
#define R_REL   64
#define D_DIM   128
#define L_LAYERS 2

#define SCAN_CHUNK 1024
#define NBLK_SCAN ((N_NODES + SCAN_CHUNK - 1) / SCAN_CHUNK)   // 98

#define LDA 136   // 128 + 8 pad (bf16 elems)
#define LDT 264   // 256 + 8 pad
#define ECAP 1024 // staged edges per block (region [32*LDA, 32*LDT) = 8192 B)

typedef __attribute__((ext_vector_type(8))) short   short8;   // 8 bf16 MFMA frag
typedef __attribute__((ext_vector_type(4))) unsigned short ushort4v;
typedef __attribute__((ext_vector_type(4))) float   f32x4;

__device__ __forceinline__ unsigned short f32_to_bf16(float f) {
  union { float f; uint32_t u; } v; v.f = f;
  uint32_t u = v.u;
  u += 0x7fffu + ((u >> 16) & 1u);   // RNE (finite inputs only)
  return (unsigned short)(u >> 16);
}
__device__ __forceinline__ float bf2f(unsigned short u) {
  union { uint32_t u; float f; } v; v.u = ((uint32_t)u) << 16; return v.f;
}

// ---------------------------------------------------------------------------
// CSR build: histogram -> 3-kernel exclusive scan -> slot scatter
// ---------------------------------------------------------------------------
__global__ __launch_bounds__(256)
void hist_kernel(const int* __restrict__ ei, int* __restrict__ deg) {
  int idx = blockIdx.x * 256 + threadIdx.x;
  atomicAdd(&deg[ei[N_EDGES + idx]], 1);
}

__global__ __launch_bounds__(256)
void scan_part1(const int* __restrict__ deg, int* __restrict__ partial) {
  __shared__ int lds[256];
  const int b = blockIdx.x, t = threadIdx.x;
  const int base = b * SCAN_CHUNK + t * 4;
  int s = 0;
  for (int k = 0; k < 4; ++k) { int i = base + k; s += (i < N_NODES) ? deg[i] : 0; }
  lds[t] = s; __syncthreads();
  for (int off = 128; off > 0; off >>= 1) {
    if (t < off) lds[t] += lds[t + off];
    __syncthreads();
  }
  if (t == 0) partial[b] = lds[0];
}

__global__ __launch_bounds__(128)
void scan_part2(int* __restrict__ partial, int* __restrict__ blockoff) {
  __shared__ int lds[128];
  const int t = threadIdx.x;
  const int v = (t < NBLK_SCAN) ? partial[t] : 0;
  lds[t] = v; __syncthreads();
  for (int off = 1; off < 128; off <<= 1) {
    int add = (t >= off) ? lds[t - off] : 0;
    __syncthreads();
    lds[t] += add;
    __syncthreads();
  }
  if (t < NBLK_SCAN) blockoff[t] = lds[t] - v;   // exclusive
}

__global__ __launch_bounds__(256)
void scan_part3(const int* __restrict__ deg, const int* __restrict__ blockoff,
                int* __restrict__ rowptr, int* __restrict__ cursor) {
  __shared__ int lds[256];
  const int b = blockIdx.x, t = threadIdx.x;
  const int base = b * SCAN_CHUNK + t * 4;
  int v[4]; int s = 0;
  for (int k = 0; k < 4; ++k) {
    int i = base + k;
    v[k] = (i < N_NODES) ? deg[i] : 0;
    s += v[k];
  }
  lds[t] = s; __syncthreads();
  for (int off = 1; off < 256; off <<= 1) {
    int add = (t >= off) ? lds[t - off] : 0;
    __syncthreads();
    lds[t] += add;
    __syncthreads();
  }
  int excl = lds[t] - s + blockoff[b];
  for (int k = 0; k < 4; ++k) {
    int i = base + k;
    if (i < N_NODES) { rowptr[i] = excl; cursor[i] = excl; excl += v[k]; }
  }
  if (b == 0 && t == 0) rowptr[N_NODES] = N_EDGES;
}

__global__ __launch_bounds__(256)
void scatter_kernel(const int* __restrict__ ei, const int* __restrict__ et,
                    int* __restrict__ cursor, int2* __restrict__ edges2) {
  int idx = blockIdx.x * 256 + threadIdx.x;
  int dst = ei[N_EDGES + idx];
  int slot = atomicAdd(&cursor[dst], 1);
  edges2[slot] = make_int2(ei[idx], et[idx]);
}

// ---------------------------------------------------------------------------
// prep: blocks [0,128): gamma/beta -> packed bf16 gbb.
//       blocks [128,384): weight f32->bf16 conversion.
// gbb layout per type t: 32 groups x (4 gamma bf16, 4 beta bf16) = 256 ushorts.
// ---------------------------------------------------------------------------
__global__ __launch_bounds__(256)
void prep_kernel(const float* __restrict__ rel_emb,
                 const float* __restrict__ rmw0, const float* __restrict__ rmb0,
                 const float* __restrict__ rmw1, const float* __restrict__ rmb1,
                 const float* __restrict__ rmw2, const float* __restrict__ rmb2,
                 const float* __restrict__ rmw3, const float* __restrict__ rmb3,
                 unsigned short* __restrict__ gbb,
                 const float* __restrict__ Ww, const float* __restrict__ mw0,
                 const float* __restrict__ mw1,
                 unsigned short* __restrict__ Wwb, unsigned short* __restrict__ mw0b,
                 unsigned short* __restrict__ mw1b) {
  if (blockIdx.x >= 128) {
    int i = (blockIdx.x - 128) * 256 + threadIdx.x;   // 0..65535
    if (i < L_LAYERS * D_DIM * D_DIM)     Wwb[i]  = f32_to_bf16(Ww[i]);
    if (i < L_LAYERS * 2 * D_DIM * D_DIM) mw0b[i] = f32_to_bf16(mw0[i]);
    if (i < L_LAYERS * 2 * D_DIM * D_DIM) mw1b[i] = f32_to_bf16(mw1[i]);
    return;
  }
  __shared__ float bufA[2 * D_DIM];
  __shared__ float bufB[2 * D_DIM];
  const int l = blockIdx.x >> 6;
  const int r = blockIdx.x & 63;
  const int j = threadIdx.x;   // 0..255

  if (j < D_DIM) bufA[j] = rel_emb[(l * R_REL + r) * D_DIM + j];
  __syncthreads();
  {
    const float* w = rmw0 + ((size_t)l * 2 * D_DIM + j) * D_DIM;
    float s = rmb0[l * 2 * D_DIM + j];
    for (int k = 0; k < D_DIM; k += 4) {
      float4 wv = *(const float4*)(w + k);
      s += wv.x * bufA[k] + wv.y * bufA[k + 1] + wv.z * bufA[k + 2] + wv.w * bufA[k + 3];
    }
    bufB[j] = fmaxf(s, 0.0f);
  }
  __syncthreads();
  {
    const float* w = rmw1 + ((size_t)l * 2 * D_DIM + j) * 2 * D_DIM;
    float s = rmb1[l * 2 * D_DIM + j];
    for (int k = 0; k < 2 * D_DIM; k += 4) {
      float4 wv = *(const float4*)(w + k);
      s += wv.x * bufB[k] + wv.y * bufB[k + 1] + wv.z * bufB[k + 2] + wv.w * bufB[k + 3];
    }
    __syncthreads();
    bufA[j] = fmaxf(s, 0.0f);
  }
  __syncthreads();
  {
    const float* w = rmw2 + ((size_t)l * 2 * D_DIM + j) * 2 * D_DIM;
    float s = rmb2[l * 2 * D_DIM + j];
    for (int k = 0; k < 2 * D_DIM; k += 4) {
      float4 wv = *(const float4*)(w + k);
      s += wv.x * bufA[k] + wv.y * bufA[k + 1] + wv.z * bufA[k + 2] + wv.w * bufA[k + 3];
    }
    __syncthreads();
    bufB[j] = fmaxf(s, 0.0f);
  }
  __syncthreads();
  {
    const float* w = rmw3 + ((size_t)l * 2 * D_DIM + j) * 2 * D_DIM;
    float s = rmb3[l * 2 * D_DIM + j];
    for (int k = 0; k < 2 * D_DIM; k += 4) {
      float4 wv = *(const float4*)(w + k);
      s += wv.x * bufB[k] + wv.y * bufB[k + 1] + wv.z * bufB[k + 2] + wv.w * bufB[k + 3];
    }
    const int t = l * R_REL + r;
    if (j < D_DIM) gbb[t * 256 + (j >> 2) * 8 + (j & 3)] = f32_to_bf16(s);          // gamma
    else { int cb = j - D_DIM;
           gbb[t * 256 + (cb >> 2) * 8 + 4 + (cb & 3)] = f32_to_bf16(s); }          // beta
  }
}

// ---------------------------------------------------------------------------
// xw = bf16( x @ Ww^T + Wb )  (N x 128). bf16 weights, direct short8 loads.
// ---------------------------------------------------------------------------
__global__ __launch_bounds__(256)
void xw_kernel(const float* __restrict__ x,
               const unsigned short* __restrict__ Wwb,  // 128x128 bf16 layer slice
               const float* __restrict__ Wb,            // 128
               unsigned short* __restrict__ xwb) {
  __shared__ unsigned short a_lds[32 * LDA];
  const int tid = threadIdx.x;
  const int m0 = blockIdx.x * 32;

  for (int i = tid; i < 1024; i += 256) {
    int row = i >> 5, ch = i & 31;
    float4 v = *(const float4*)&x[(m0 + row) * D_DIM + ch * 4];
    ushort4v s;
    s[0] = f32_to_bf16(v.x); s[1] = f32_to_bf16(v.y);
    s[2] = f32_to_bf16(v.z); s[3] = f32_to_bf16(v.w);
    *(ushort4v*)&a_lds[row * LDA + ch * 4] = s;
  }
  __syncthreads();

  const int wave = tid >> 6, lane = tid & 63;
  const int lrow = lane & 15, quad = lane >> 4;
  const int n0 = wave * 32;

  f32x4 acc[2][2] = {};
  for (int ks = 0; ks < 128; ks += 32) {
    short8 a0 = *(const short8*)&a_lds[lrow * LDA + ks + quad * 8];
    short8 a1 = *(const short8*)&a_lds[(16 + lrow) * LDA + ks + quad * 8];
    short8 b0 = *(const short8*)&Wwb[(n0 + lrow) * D_DIM + ks + quad * 8];
    short8 b1 = *(const short8*)&Wwb[(n0 + 16 + lrow) * D_DIM + ks + quad * 8];
    acc[0][0] = __builtin_amdgcn_mfma_f32_16x16x32_bf16(a0, b0, acc[0][0], 0, 0, 0);
    acc[0][1] = __builtin_amdgcn_mfma_f32_16x16x32_bf16(a0, b1, acc[0][1], 0, 0, 0);
    acc[1][0] = __builtin_amdgcn_mfma_f32_16x16x32_bf16(a1, b0, acc[1][0], 0, 0, 0);
    acc[1][1] = __builtin_amdgcn_mfma_f32_16x16x32_bf16(a1, b1, acc[1][1], 0, 0, 0);
  }

  for (int mt = 0; mt < 2; ++mt)
    for (int nt = 0; nt < 2; ++nt)
      for (int rr = 0; rr < 4; ++rr) {
        int row = mt * 16 + quad * 4 + rr;
        int col = n0 + nt * 16 + lrow;
        xwb[(size_t)(m0 + row) * D_DIM + col] = f32_to_bf16(acc[mt][nt][rr] + Wb[col]);
      }
}

// ---------------------------------------------------------------------------
// Fused gather + node MLP. Block = 32 nodes, 4 waves.
// Phase A0: stage rowptr[m0..m0+32] and the block's contiguous CSR edge slice
//           into LDS (region unused by the A-tile).
// Phase A:  wave w gathers nodes [8w, 8w+8): 32 lanes x 4 cols; halves take
//           alternate edges; shfl_xor(32) combines; o=(1+eps)x+aggr -> bf16 A-tile.
// Phase B:  t = relu(o @ w0^T + b0) -> LDS (overlay, stride LDT).
// Phase C:  y = t @ w1^T + b1 -> global.
// ---------------------------------------------------------------------------
__global__ __launch_bounds__(256)
void gather_mlp_kernel(const int2* __restrict__ edges2, const int* __restrict__ rowptr,
                       const float* __restrict__ x, const unsigned short* __restrict__ xwb,
                       const unsigned short* __restrict__ gbb,
                       const float* __restrict__ eps,
                       const unsigned short* __restrict__ w0b, const float* __restrict__ b0,
                       const unsigned short* __restrict__ w1b, const float* __restrict__ b1,
                       float* __restrict__ y) {
  __shared__ unsigned short u_lds[32 * LDT];   // 16896 B, phases overlay
  __shared__ int rp_lds[33];
  unsigned short* a_lds = u_lds;               // stride LDA (phase A write / B read)
  unsigned short* t_lds = u_lds;               // stride LDT (phase B write / C read)
  int2* es = (int2*)(u_lds + 32 * LDA);        // phase-A-only region, 1024 edges

  const int tid = threadIdx.x;
  const int m0 = blockIdx.x * 32;
  const int wave = tid >> 6, lane = tid & 63;
  const float e1v = 1.0f + eps[0];

  // ---- phase A0: stage rowptr slice + edge slice
  if (tid < 33) rp_lds[tid] = rowptr[m0 + tid];
  const int beg0 = rowptr[m0];
  const int nE = rowptr[m0 + 32] - beg0;
  for (int i = tid; i < nE && i < ECAP; i += 256) es[i] = edges2[beg0 + i];
  __syncthreads();

  // ---- phase A: gather 8 nodes per wave, 2 edges in flight via wave halves
  const int half = lane >> 5;        // 0/1: alternate edges
  const int s    = lane & 31;
  const int c    = s * 4;            // 4 cols per lane
  for (int i = 0; i < 8; ++i) {
    const int row  = wave * 8 + i;
    const int node = m0 + row;
    const int beg = rp_lds[row], end = rp_lds[row + 1];
    f32x4 acc = {0.0f, 0.0f, 0.0f, 0.0f};
    for (int e = beg + half; e < end; e += 2) {
      const int le = e - beg0;
      int2 ed;
      if (le < ECAP) ed = es[le]; else ed = edges2[e];
      ushort4v xu = *(const ushort4v*)&xwb[(size_t)ed.x * D_DIM + c];
      short8   gb = *(const short8*)&gbb[ed.y * 256 + s * 8];
      acc[0] += bf2f((unsigned short)gb[0]) * bf2f(xu[0]) + bf2f((unsigned short)gb[4]);
      acc[1] += bf2f((unsigned short)gb[1]) * bf2f(xu[1]) + bf2f((unsigned short)gb[5]);
      acc[2] += bf2f((unsigned short)gb[2]) * bf2f(xu[2]) + bf2f((unsigned short)gb[6]);
      acc[3] += bf2f((unsigned short)gb[3]) * bf2f(xu[3]) + bf2f((unsigned short)gb[7]);
    }
    acc[0] += __shfl_xor(acc[0], 32);
    acc[1] += __shfl_xor(acc[1], 32);
    acc[2] += __shfl_xor(acc[2], 32);
    acc[3] += __shfl_xor(acc[3], 32);
    if (half == 0) {
      float4 xo = *(const float4*)&x[(size_t)node * D_DIM + c];
      ushort4v o4;
      o4[0] = f32_to_bf16(e1v * xo.x + acc[0]);
      o4[1] = f32_to_bf16(e1v * xo.y + acc[1]);
      o4[2] = f32_to_bf16(e1v * xo.z + acc[2]);
      o4[3] = f32_to_bf16(e1v * xo.w + acc[3]);
      *(ushort4v*)&a_lds[row * LDA + c] = o4;
    }
  }
  __syncthreads();

  const int lrow = lane & 15, quad = lane >> 4;

  // ---- phase B: t = relu(o @ w0^T + b0); wave covers cols [wave*64, +64)
  {
    const int n0 = wave * 64;
    f32x4 acc[2][4] = {};
    for (int ks = 0; ks < 128; ks += 32) {
      short8 a0 = *(const short8*)&a_lds[lrow * LDA + ks + quad * 8];
      short8 a1 = *(const short8*)&a_lds[(16 + lrow) * LDA + ks + quad * 8];
      for (int nt = 0; nt < 4; ++nt) {
        short8 b = *(const short8*)&w0b[(n0 + nt * 16 + lrow) * D_DIM + ks + quad * 8];
        acc[0][nt] = __builtin_amdgcn_mfma_f32_16x16x32_bf16(a0, b, acc[0][nt], 0, 0, 0);
        acc[1][nt] = __builtin_amdgcn_mfma_f32_16x16x32_bf16(a1, b, acc[1][nt], 0, 0, 0);
      }
    }
    __syncthreads();   // all waves done reading A-tile before overlay write
    for (int mt = 0; mt < 2; ++mt)
      for (int nt = 0; nt < 4; ++nt)
        for (int rr = 0; rr < 4; ++rr) {
          int row = mt * 16 + quad * 4 + rr;
          int col = n0 + nt * 16 + lrow;
          float v = acc[mt][nt][rr] + b0[col];
          t_lds[row * LDT + col] = f32_to_bf16(fmaxf(v, 0.0f));
        }
  }
  __syncthreads();

  // ---- phase C: y = t @ w1^T + b1; wave covers cols [wave*32, +32)
  {
    const int n0 = wave * 32;
    f32x4 acc[2][2] = {};
    for (int ks = 0; ks < 256; ks += 32) {
      short8 a0 = *(const short8*)&t_lds[lrow * LDT + ks + quad * 8];
      short8 a1 = *(const short8*)&t_lds[(16 + lrow) * LDT + ks + quad * 8];
      for (int nt = 0; nt < 2; ++nt) {
        short8 b = *(const short8*)&w1b[(n0 + nt * 16 + lrow) * 2 * D_DIM + ks + quad * 8];
        acc[0][nt] = __builtin_amdgcn_mfma_f32_16x16x32_bf16(a0, b, acc[0][nt], 0, 0, 0);
        acc[1][nt] = __builtin_amdgcn_mfma_f32_16x16x32_bf16(a1, b, acc[1][nt], 0, 0, 0);
      }
    }
    for (int mt = 0; mt < 2; ++mt)
      for (int nt = 0; nt < 2; ++nt)
        for (int rr = 0; rr < 4; ++rr) {
          int row = mt * 16 + quad * 4 + rr;
          int col = n0 + nt * 16 + lrow;
          y[(size_t)(m0 + row) * D_DIM + col] = acc[mt][nt][rr] + b1[col];
        }
  }
}

// ---------------------------------------------------------------------------
extern "C" void kernel_launch(void* const* d_in, const int* in_sizes, int n_in,
                              void* d_out, int out_size, void* d_ws, size_t ws_size,
                              hipStream_t stream) {
  const int*   ei      = (const int*)d_in[0];
  const int*   et      = (const int*)d_in[1];
  const float* embed   = (const float*)d_in[2];
  const float* rel_emb = (const float*)d_in[3];
  const float* rmw0 = (const float*)d_in[4];  const float* rmb0 = (const float*)d_in[5];
  const float* rmw1 = (const float*)d_in[6];  const float* rmb1 = (const float*)d_in[7];
  const float* rmw2 = (const float*)d_in[8];  const float* rmb2 = (const float*)d_in[9];
  const float* rmw3 = (const float*)d_in[10]; const float* rmb3 = (const float*)d_in[11];
  const float* Ww   = (const float*)d_in[12]; const float* Wb   = (const float*)d_in[13];
  const float* mw0  = (const float*)d_in[14]; const float* mb0  = (const float*)d_in[15];
  const float* mw1  = (const float*)d_in[16]; const float* mb1  = (const float*)d_in[17];
  const float* eps  = (const float*)d_in[18];
  float* out = (float*)d_out;

  // workspace layout
  float*          W1   = (float*)d_ws;                          // N*D f32
  unsigned short* xwb  = (unsigned short*)(W1 + (size_t)N_NODES * D_DIM);  // N*D bf16
  unsigned short* gbb  = xwb + (size_t)N_NODES * D_DIM;         // L*R*256 bf16
  unsigned short* Wwb  = gbb + L_LAYERS * R_REL * 256;          // L*128*128
  unsigned short* mw0b = Wwb + L_LAYERS * D_DIM * D_DIM;        // L*256*128
  unsigned short* mw1b = mw0b + L_LAYERS * 2 * D_DIM * D_DIM;   // L*128*256
  int*   deg     = (int*)(mw1b + L_LAYERS * 2 * D_DIM * D_DIM); // N
  int*   rowptr  = deg + N_NODES;                               // N+1
  int*   cursor  = rowptr + N_NODES + 1;                        // N
  int*   partial = cursor + N_NODES;                            // NBLK_SCAN
  int*   blockoff= partial + NBLK_SCAN;                         // NBLK_SCAN
  int2*  edges2  = (int2*)(blockoff + NBLK_SCAN + 1);           // E int2

  // ---- one-shot preprocessing
  hipMemsetAsync(deg, 0, N_NODES * sizeof(int), stream);
  hist_kernel<<<N_EDGES / 256, 256, 0, stream>>>(ei, deg);
  scan_part1<<<NBLK_SCAN, 256, 0, stream>>>(deg, partial);
  scan_part2<<<1, 128, 0, stream>>>(partial, blockoff);
  scan_part3<<<NBLK_SCAN, 256, 0, stream>>>(deg, blockoff, rowptr, cursor);
  scatter_kernel<<<N_EDGES / 256, 256, 0, stream>>>(ei, et, cursor, edges2);
  prep_kernel<<<384, 256, 0, stream>>>(rel_emb, rmw0, rmb0, rmw1, rmb1,
                                       rmw2, rmb2, rmw3, rmb3, gbb,
                                       Ww, mw0, mw1, Wwb, mw0b, mw1b);

  const int gN = N_NODES / 32;        // 3125

  // ---- layer 0: x = embed -> xwb -> fused gather+mlp -> W1
  xw_kernel<<<gN, 256, 0, stream>>>(embed, Wwb, Wb, xwb);
  gather_mlp_kernel<<<gN, 256, 0, stream>>>(edges2, rowptr, embed, xwb, gbb, eps,
                                            mw0b, mb0, mw1b, mb1, W1);

  // ---- layer 1: x = W1 -> xwb -> fused gather+mlp -> d_out
  xw_kernel<<<gN, 256, 0, stream>>>(W1, Wwb + D_DIM * D_DIM, Wb + D_DIM, xwb);
  gather_mlp_kernel<<<gN, 256, 0, stream>>>(edges2, rowptr, W1, xwb,
                                            gbb + R_REL * 256, eps + 1,
                                            mw0b + 2 * D_DIM * D_DIM, mb0 + 2 * D_DIM,
                                            mw1b + 2 * D_DIM * D_DIM, mb1 + D_DIM, out);
}